// Round 7
// baseline (1433.842 us; speedup 1.0000x reference)
//
#include <hip/hip_runtime.h>
#include <hip/hip_bf16.h>
#include <type_traits>

typedef __attribute__((ext_vector_type(8))) __bf16 bf16x8;
typedef __attribute__((ext_vector_type(4))) float f32x4;

#define NN 100000
#define NE 1600000
#define NBUCK 1563        // ceil(NN/64) buckets of 64 nodes
#define ECHUNK 200000     // NE/8 edges per chunk-group

// ---------------- converts: weights (transpose+bf16) and x (bf16), one kernel ----------------
__global__ void convert_kernel(const float* __restrict__ W1, const float* __restrict__ W2,
                               __bf16* __restrict__ W1T, __bf16* __restrict__ W2T,
                               const float4* __restrict__ x4, uint2* __restrict__ xb) {
    int tid = blockIdx.x * 256 + threadIdx.x;
    if (tid < 128 * 256) {
        int k1 = tid >> 8, n1 = tid & 255;             // W1 is [128][256]
        W1T[n1 * 128 + k1] = (__bf16)W1[tid];
        int k2 = tid >> 7, n2 = tid & 127;             // W2 is [256][128]
        W2T[n2 * 256 + k2] = (__bf16)W2[tid];
    } else {
        int i = tid - 128 * 256;
        if (i < NN * 32) {                             // n4 = NN*128/4
            float4 v = x4[i];
            __bf16 b0 = (__bf16)v.x, b1 = (__bf16)v.y, b2 = (__bf16)v.z, b3 = (__bf16)v.w;
            uint2 o;
            o.x = (unsigned)*(unsigned short*)&b0 | ((unsigned)*(unsigned short*)&b1 << 16);
            o.y = (unsigned)*(unsigned short*)&b2 | ((unsigned)*(unsigned short*)&b3 << 16);
            xb[i] = o;
        }
    }
}

// ---------------- bucket-granular CSR build ----------------
// Chunk-partitioned: group g = blockIdx&7 (XCD g) reads edge chunk g ONCE,
// counts into its private cnt8[g*NBUCK..] (6.25KB, XCD-local atomics).
__global__ void hist_bucket8(const int* __restrict__ edst, int* __restrict__ cnt8) {
    int grp  = blockIdx.x & 7;
    int blk  = blockIdx.x >> 3;
    int nblk = gridDim.x >> 3;
    int* my = cnt8 + grp * NBUCK;
    int lo = grp * ECHUNK, hi = lo + ECHUNK;
    if (hi > NE) hi = NE;
    for (int e = lo + blk * 256 + threadIdx.x; e < hi; e += nblk * 256)
        atomicAdd(&my[edst[e] >> 6], 1);
}

// One block: bucket_off = exclusive scan of per-bucket totals; cursor8[g][b] =
// bucket_off[b] + sum_{g'<g} cnt8[g'][b]  (per-group slice starts).
__global__ void scan_all(const int* __restrict__ cnt8, int* __restrict__ bucket_off,
                         int* __restrict__ cursor8) {
    __shared__ int sm[256];
    __shared__ int carry;
    int t = threadIdx.x;
    if (t == 0) carry = 0;
    __syncthreads();
    for (int base = 0; base < NBUCK; base += 256) {
        int b = base + t;
        int c[8]; int tot = 0;
        if (b < NBUCK) {
#pragma unroll
            for (int g = 0; g < 8; ++g) { c[g] = cnt8[g * NBUCK + b]; tot += c[g]; }
        }
        sm[t] = tot; __syncthreads();
        for (int off = 1; off < 256; off <<= 1) {
            int add = (t >= off) ? sm[t - off] : 0;
            __syncthreads();
            sm[t] += add;
            __syncthreads();
        }
        int excl = carry + sm[t] - tot;
        if (b < NBUCK) {
            bucket_off[b] = excl;
            int run = excl;
#pragma unroll
            for (int g = 0; g < 8; ++g) { cursor8[g * NBUCK + b] = run; run += c[g]; }
        }
        __syncthreads();
        if (t == 255) carry += sm[255];
        __syncthreads();
    }
    if (t == 0) bucket_off[NBUCK] = NE;
}

// Chunk-partitioned binned scatter: only 1563 write streams per group ->
// pairs lines fill completely in L2 before writeback (no amplification).
// pairs[pos] = {(src<<8)|(dst&63), val_bits}
__global__ void reorder_bucket8(const int* __restrict__ esrc, const int* __restrict__ edst,
                                const float* __restrict__ ev,
                                int* cursor8, int2* __restrict__ pairs) {
    int grp  = blockIdx.x & 7;
    int blk  = blockIdx.x >> 3;
    int nblk = gridDim.x >> 3;
    int* cur = cursor8 + grp * NBUCK;
    int lo = grp * ECHUNK, hi = lo + ECHUNK;
    if (hi > NE) hi = NE;
    for (int e = lo + blk * 256 + threadIdx.x; e < hi; e += nblk * 256) {
        int d = edst[e];
        int s = esrc[e];
        float v = ev[e];
        int pos = atomicAdd(&cur[d >> 6], 1);
        int2 p; p.x = (s << 8) | (d & 63); p.y = __float_as_int(v);
        pairs[pos] = p;
    }
}

// ---------------- gather with LDS accumulation: one block per 64-node bucket ----------------
__device__ __forceinline__ float bflo(unsigned w) { return __uint_as_float(w << 16); }
__device__ __forceinline__ float bfhi(unsigned w) { return __uint_as_float(w & 0xffff0000u); }

__global__ __launch_bounds__(256) void gather_lds_kernel(const unsigned* __restrict__ xb,
                                                         const int* __restrict__ bucket_off,
                                                         const int2* __restrict__ pairs,
                                                         const float* __restrict__ eps,
                                                         uint2* __restrict__ AXb) {
    __shared__ float acc[64][128];
    const int t = threadIdx.x;
    // zero 8192 floats
#pragma unroll
    for (int k = 0; k < 32; ++k) ((float*)acc)[k * 256 + t] = 0.0f;
    __syncthreads();

    const int b = blockIdx.x;
    const int beg = bucket_off[b], end = bucket_off[b + 1];
    const int wave = t >> 6, lane = t & 63;
    const int cnt = end - beg;
    const int per = (cnt + 3) >> 2;
    const int wbeg = beg + wave * per;
    const int wend = min(wbeg + per, end);
    const char* xbase = (const char*)xb + lane * 4;
    const int l2 = lane * 2;

#define EDGE(i)                                                             \
    {                                                                       \
        int sx  = __shfl(meta.x, (i));                                      \
        float v = __int_as_float(__shfl(meta.y, (i)));                      \
        unsigned w = *(const unsigned*)(xbase + (sx & 0xffffff00));         \
        int row = sx & 63;                                                  \
        atomicAdd(&acc[row][l2],     v * bflo(w));                          \
        atomicAdd(&acc[row][l2 + 1], v * bfhi(w));                          \
    }

    for (int base = wbeg; base < wend; base += 64) {
        int m = wend - base; if (m > 64) m = 64;
        int2 meta = pairs[base + (lane < m ? lane : m - 1)];
        if (m == 64) {
#pragma unroll
            for (int i = 0; i < 64; ++i) EDGE(i)
        } else {
            for (int i = 0; i < m; ++i) EDGE(i)
        }
    }
#undef EDGE
    __syncthreads();

    // epilogue: AXb[node] = bf16( acc + (1+eps)*x[node] )
    const int r = t >> 2;                 // 0..63, node row within bucket
    const int c = (t & 3) * 16;           // uint column start (of 64)
    const int n = b * 64 + r;
    if (n < NN) {
        const float sc = 1.0f + eps[0];
        const unsigned* xr = xb + (size_t)n * 64 + c;
        uint2* op = AXb + ((size_t)n * 64 + c) / 2;
#pragma unroll
        for (int k = 0; k < 16; k += 2) {
            unsigned w0 = xr[k], w1 = xr[k + 1];
            float f0 = acc[r][(c + k) * 2]     + sc * bflo(w0);
            float f1 = acc[r][(c + k) * 2 + 1] + sc * bfhi(w0);
            float f2 = acc[r][(c + k) * 2 + 2] + sc * bflo(w1);
            float f3 = acc[r][(c + k) * 2 + 3] + sc * bfhi(w1);
            __bf16 b0 = (__bf16)f0, b1 = (__bf16)f1, b2 = (__bf16)f2, b3 = (__bf16)f3;
            uint2 o;
            o.x = (unsigned)*(unsigned short*)&b0 | ((unsigned)*(unsigned short*)&b1 << 16);
            o.y = (unsigned)*(unsigned short*)&b2 | ((unsigned)*(unsigned short*)&b3 << 16);
            op[k / 2] = o;
        }
    }
}

// ---------------- fallback path (atomic scatter, fp32 AX in d_out) ----------------
__global__ void init_ax_kernel(const float4* __restrict__ x, float4* __restrict__ AX,
                               const float* __restrict__ eps, int n4) {
    int i = blockIdx.x * blockDim.x + threadIdx.x;
    if (i >= n4) return;
    float s = 1.0f + eps[0];
    float4 v = x[i];
    v.x *= s; v.y *= s; v.z *= s; v.w *= s;
    AX[i] = v;
}

__global__ void scatter_kernel(const float2* __restrict__ x2, const float* __restrict__ ev,
                               const int* __restrict__ esrc, const int* __restrict__ edst,
                               float* AX) {
    unsigned gid = blockIdx.x * 256u + threadIdx.x;
    unsigned e = gid >> 6;
    unsigned lane = gid & 63u;
    if (e >= NE) return;
    float v = ev[e];
    int s = esrc[e], d = edst[e];
    float2 xv = x2[(size_t)s * 64 + lane];
    float* dstp = AX + (size_t)d * 128 + lane * 2;
    atomicAdd(dstp,     v * xv.x);
    atomicAdd(dstp + 1, v * xv.y);
}

// ---------------- fused 2-layer MLP: out = relu(A@W1+b1)@W2+b2, A is bf16 or fp32 ----------------
template <typename AT>
__global__ __launch_bounds__(256) void mlp_kernel(const AT* A,
                                                  const __bf16* __restrict__ W1T,
                                                  const __bf16* __restrict__ W2T,
                                                  const float* __restrict__ b1,
                                                  const float* __restrict__ b2,
                                                  float* out) {
    __shared__ __bf16 Hl[64][264];

    const int wave = threadIdx.x >> 6;
    const int lane = threadIdx.x & 63;
    const int l15  = lane & 15;
    const int lhi  = lane >> 4;
    const int rowbase = blockIdx.x * 64;

    f32x4 acc1[4][4] = {};
#pragma unroll
    for (int ks = 0; ks < 4; ++ks) {
        const int k0 = ks * 32 + lhi * 8;
        bf16x8 am[4], bn[4];
#pragma unroll
        for (int mt = 0; mt < 4; ++mt) {
            int row = rowbase + mt * 16 + l15;
            if (row >= NN) row = NN - 1;
            if constexpr (std::is_same<AT, __bf16>::value) {
                am[mt] = *(const bf16x8*)(A + (size_t)row * 128 + k0);
            } else {
                const float4* ap = (const float4*)(A + (size_t)row * 128 + k0);
                float4 f0 = ap[0], f1 = ap[1];
                bf16x8 a;
                a[0]=(__bf16)f0.x; a[1]=(__bf16)f0.y; a[2]=(__bf16)f0.z; a[3]=(__bf16)f0.w;
                a[4]=(__bf16)f1.x; a[5]=(__bf16)f1.y; a[6]=(__bf16)f1.z; a[7]=(__bf16)f1.w;
                am[mt] = a;
            }
        }
#pragma unroll
        for (int nt = 0; nt < 4; ++nt) {
            int n = wave * 64 + nt * 16 + l15;
            bn[nt] = *(const bf16x8*)(W1T + (size_t)n * 128 + k0);
        }
#pragma unroll
        for (int mt = 0; mt < 4; ++mt)
#pragma unroll
            for (int nt = 0; nt < 4; ++nt)
                acc1[mt][nt] = __builtin_amdgcn_mfma_f32_16x16x32_bf16(am[mt], bn[nt], acc1[mt][nt], 0, 0, 0);
    }

#pragma unroll
    for (int nt = 0; nt < 4; ++nt) {
        int n = wave * 64 + nt * 16 + l15;
        float bias = b1[n];
#pragma unroll
        for (int mt = 0; mt < 4; ++mt)
#pragma unroll
            for (int r = 0; r < 4; ++r) {
                float h = acc1[mt][nt][r] + bias;
                Hl[mt * 16 + lhi * 4 + r][n] = (__bf16)fmaxf(h, 0.0f);
            }
    }
    __syncthreads();

    f32x4 acc2[4][2] = {};
#pragma unroll
    for (int ks = 0; ks < 8; ++ks) {
        const int k0 = ks * 32 + lhi * 8;
        bf16x8 ha[4], wb[2];
#pragma unroll
        for (int mt = 0; mt < 4; ++mt)
            ha[mt] = *(const bf16x8*)(&Hl[mt * 16 + l15][k0]);
#pragma unroll
        for (int nt = 0; nt < 2; ++nt) {
            int n = wave * 32 + nt * 16 + l15;
            wb[nt] = *(const bf16x8*)(W2T + (size_t)n * 256 + k0);
        }
#pragma unroll
        for (int mt = 0; mt < 4; ++mt)
#pragma unroll
            for (int nt = 0; nt < 2; ++nt)
                acc2[mt][nt] = __builtin_amdgcn_mfma_f32_16x16x32_bf16(ha[mt], wb[nt], acc2[mt][nt], 0, 0, 0);
    }

#pragma unroll
    for (int nt = 0; nt < 2; ++nt) {
        int n = wave * 32 + nt * 16 + l15;
        float bias = b2[n];
#pragma unroll
        for (int mt = 0; mt < 4; ++mt)
#pragma unroll
            for (int r = 0; r < 4; ++r) {
                int row = rowbase + mt * 16 + lhi * 4 + r;
                if (row < NN) out[(size_t)row * 128 + n] = acc2[mt][nt][r] + bias;
            }
    }
}

extern "C" void kernel_launch(void* const* d_in, const int* in_sizes, int n_in,
                              void* d_out, int out_size, void* d_ws, size_t ws_size,
                              hipStream_t stream) {
    const float* x    = (const float*)d_in[0];
    const float* ev   = (const float*)d_in[1];
    const float* W1   = (const float*)d_in[2];
    const float* b1   = (const float*)d_in[3];
    const float* W2   = (const float*)d_in[4];
    const float* b2   = (const float*)d_in[5];
    const float* eps  = (const float*)d_in[6];
    const int*   esrc = (const int*)d_in[7];
    const int*   edst = (const int*)d_in[8];
    float* out = (float*)d_out;

    char* ws = (char*)d_ws;
    size_t off = 0;
    auto alloc = [&](size_t bytes) { void* p = ws + off; off += (bytes + 511) & ~size_t(511); return p; };

    __bf16* W1T     = (__bf16*)alloc(128 * 256 * sizeof(__bf16));
    __bf16* W2T     = (__bf16*)alloc(128 * 256 * sizeof(__bf16));
    int* cnt8       = (int*)  alloc((size_t)8 * NBUCK * sizeof(int));
    int* bucket_off = (int*)  alloc((NBUCK + 1) * sizeof(int));
    int* cursor8    = (int*)  alloc((size_t)8 * NBUCK * sizeof(int));
    int2* pairs     = (int2*) alloc((size_t)NE * sizeof(int2));
    unsigned* xb    = (unsigned*)alloc((size_t)NN * 64 * sizeof(unsigned));   // bf16 x
    unsigned* AXb   = (unsigned*)alloc((size_t)NN * 64 * sizeof(unsigned));   // bf16 AX
    bool csr_ok = (off <= ws_size);

    int nblk = (NN + 63) / 64;   // 1563
    if (csr_ok) {
        int cblocks = 128 + (NN * 32 + 255) / 256;   // weights + x converts
        convert_kernel<<<cblocks, 256, 0, stream>>>(W1, W2, W1T, W2T, (const float4*)x, (uint2*)xb);
        hipMemsetAsync(cnt8, 0, (size_t)8 * NBUCK * sizeof(int), stream);
        hist_bucket8<<<2048, 256, 0, stream>>>(edst, cnt8);
        scan_all<<<1, 256, 0, stream>>>(cnt8, bucket_off, cursor8);
        reorder_bucket8<<<2048, 256, 0, stream>>>(esrc, edst, ev, cursor8, pairs);
        gather_lds_kernel<<<NBUCK, 256, 0, stream>>>(xb, bucket_off, pairs, eps, (uint2*)AXb);
        mlp_kernel<__bf16><<<nblk, 256, 0, stream>>>((const __bf16*)AXb, W1T, W2T, b1, b2, out);
    } else {
        // fallback: atomic scatter path (fp32 AX in d_out)
        __bf16* W1Tf = (__bf16*)ws;
        __bf16* W2Tf = W1Tf + 128 * 256;
        convert_kernel<<<128, 256, 0, stream>>>(W1, W2, W1Tf, W2Tf, (const float4*)x, (uint2*)nullptr);
        int n4 = NN * 128 / 4;
        init_ax_kernel<<<(n4 + 255) / 256, 256, 0, stream>>>((const float4*)x, (float4*)out, eps, n4);
        scatter_kernel<<<(NE * 64u) / 256u, 256, 0, stream>>>((const float2*)x, ev, esrc, edst, out);
        mlp_kernel<float><<<nblk, 256, 0, stream>>>(out, W1Tf, W2Tf, b1, b2, out);
    }
}

// Round 8
// 303.333 us; speedup vs baseline: 4.7270x; 4.7270x over previous
//
#include <hip/hip_runtime.h>
#include <hip/hip_bf16.h>
#include <type_traits>

typedef __attribute__((ext_vector_type(8))) __bf16 bf16x8;
typedef __attribute__((ext_vector_type(4))) float f32x4;

#define NN 100000
#define NE 1600000
#define NBUCK 1563        // ceil(NN/64) buckets of 64 nodes
#define ECHUNK 200000     // NE/8 edges per chunk-group

// ---------------- converts: weights (transpose+bf16) and x (bf16), one kernel ----------------
__global__ void convert_kernel(const float* __restrict__ W1, const float* __restrict__ W2,
                               __bf16* __restrict__ W1T, __bf16* __restrict__ W2T,
                               const float4* __restrict__ x4, uint2* __restrict__ xb) {
    int tid = blockIdx.x * 256 + threadIdx.x;
    if (tid < 128 * 256) {
        int k1 = tid >> 8, n1 = tid & 255;             // W1 is [128][256]
        W1T[n1 * 128 + k1] = (__bf16)W1[tid];
        int k2 = tid >> 7, n2 = tid & 127;             // W2 is [256][128]
        W2T[n2 * 256 + k2] = (__bf16)W2[tid];
    } else {
        int i = tid - 128 * 256;
        if (i < NN * 32) {                             // n4 = NN*128/4
            float4 v = x4[i];
            __bf16 b0 = (__bf16)v.x, b1 = (__bf16)v.y, b2 = (__bf16)v.z, b3 = (__bf16)v.w;
            uint2 o;
            o.x = (unsigned)*(unsigned short*)&b0 | ((unsigned)*(unsigned short*)&b1 << 16);
            o.y = (unsigned)*(unsigned short*)&b2 | ((unsigned)*(unsigned short*)&b3 << 16);
            xb[i] = o;
        }
    }
}

// ---------------- bucket-granular CSR build ----------------
__global__ void hist_bucket8(const int* __restrict__ edst, int* __restrict__ cnt8) {
    int grp  = blockIdx.x & 7;
    int blk  = blockIdx.x >> 3;
    int nblk = gridDim.x >> 3;
    int* my = cnt8 + grp * NBUCK;
    int lo = grp * ECHUNK, hi = lo + ECHUNK;
    if (hi > NE) hi = NE;
    for (int e = lo + blk * 256 + threadIdx.x; e < hi; e += nblk * 256)
        atomicAdd(&my[edst[e] >> 6], 1);
}

// One block: bucket_off = exclusive scan of per-bucket totals; cursor8[g][b] =
// per-group slice starts within each bucket's range.
__global__ void scan_all(const int* __restrict__ cnt8, int* __restrict__ bucket_off,
                         int* __restrict__ cursor8) {
    __shared__ int sm[256];
    __shared__ int carry;
    int t = threadIdx.x;
    if (t == 0) carry = 0;
    __syncthreads();
    for (int base = 0; base < NBUCK; base += 256) {
        int b = base + t;
        int c[8]; int tot = 0;
        if (b < NBUCK) {
#pragma unroll
            for (int g = 0; g < 8; ++g) { c[g] = cnt8[g * NBUCK + b]; tot += c[g]; }
        }
        sm[t] = tot; __syncthreads();
        for (int off = 1; off < 256; off <<= 1) {
            int add = (t >= off) ? sm[t - off] : 0;
            __syncthreads();
            sm[t] += add;
            __syncthreads();
        }
        int excl = carry + sm[t] - tot;
        if (b < NBUCK) {
            bucket_off[b] = excl;
            int run = excl;
#pragma unroll
            for (int g = 0; g < 8; ++g) { cursor8[g * NBUCK + b] = run; run += c[g]; }
        }
        __syncthreads();
        if (t == 255) carry += sm[255];
        __syncthreads();
    }
    if (t == 0) bucket_off[NBUCK] = NE;
}

// Chunk-partitioned binned scatter: 1563 write streams per group -> lines fill
// in L2 before writeback. pairs[pos] = {(src<<8)|(dst&63), val_bits}
__global__ void reorder_bucket8(const int* __restrict__ esrc, const int* __restrict__ edst,
                                const float* __restrict__ ev,
                                int* cursor8, int2* __restrict__ pairs) {
    int grp  = blockIdx.x & 7;
    int blk  = blockIdx.x >> 3;
    int nblk = gridDim.x >> 3;
    int* cur = cursor8 + grp * NBUCK;
    int lo = grp * ECHUNK, hi = lo + ECHUNK;
    if (hi > NE) hi = NE;
    for (int e = lo + blk * 256 + threadIdx.x; e < hi; e += nblk * 256) {
        int d = edst[e];
        int s = esrc[e];
        float v = ev[e];
        int pos = atomicAdd(&cur[d >> 6], 1);
        int2 p; p.x = (s << 8) | (d & 63); p.y = __float_as_int(v);
        pairs[pos] = p;
    }
}

// ---------------- local sort: bucket slice -> node-sorted pairs2 + node_off ----------------
// One block per bucket. Pass A counts 64 rows (LDS atomics), wave-0 exclusive
// scan, pass B scatters into pairs2 (writes stay in this bucket's hot slice).
__global__ __launch_bounds__(256) void local_sort_kernel(const int* __restrict__ bucket_off,
                                                         const int2* __restrict__ pt,
                                                         int2* __restrict__ ps,
                                                         int* __restrict__ node_off) {
    __shared__ int rcnt[64];
    __shared__ int rcur[64];
    const int b = blockIdx.x;
    const int t = threadIdx.x;
    const int beg = bucket_off[b], end = bucket_off[b + 1];
    if (t < 64) rcnt[t] = 0;
    __syncthreads();
    for (int i = beg + t; i < end; i += 256)
        atomicAdd(&rcnt[pt[i].x & 63], 1);
    __syncthreads();
    if (t < 64) {                       // wave 0: exclusive scan of 64 counts
        int v = rcnt[t];
        int s = v;
#pragma unroll
        for (int off = 1; off < 64; off <<= 1) {
            int u = __shfl_up(s, off);
            if (t >= off) s += u;
        }
        int excl = s - v;
        rcur[t] = excl;
        node_off[b * 64 + t] = beg + excl;
    }
    __syncthreads();
    for (int i = beg + t; i < end; i += 256) {
        int2 p = pt[i];
        int r = p.x & 63;
        int pos = beg + atomicAdd(&rcur[r], 1);
        int2 q; q.x = p.x & 0xffffff00; q.y = p.y;   // {src byte-offset, val}
        ps[pos] = q;
    }
}

// ---------------- per-node gather reduce (bf16 x, 2 edges/wave) ----------------
__device__ __forceinline__ float bflo(unsigned w) { return __uint_as_float(w << 16); }
__device__ __forceinline__ float bfhi(unsigned w) { return __uint_as_float(w & 0xffff0000u); }

__global__ __launch_bounds__(256) void gather_reduce_kernel(const unsigned* __restrict__ xb,
                                                            const int* __restrict__ node_off,
                                                            const int2* __restrict__ pairs,
                                                            const float* __restrict__ eps,
                                                            uint2* __restrict__ AXb) {
    unsigned gid = blockIdx.x * 256u + threadIdx.x;
    unsigned n = gid >> 6, lane = gid & 63u;
    if (n >= NN) return;
    const unsigned hw = lane >> 5, l32 = lane & 31u;
    const int beg = node_off[n], end = node_off[n + 1];
    const char* xbase = (const char*)xb + l32 * 8;   // this lane's 8B slot within any row
    float a0 = 0.f, a1 = 0.f, a2 = 0.f, a3 = 0.f;
    int j = beg + (int)hw;
    for (; j + 2 < end; j += 4) {                    // 2 edges per half per iter
        int2 pA = pairs[j], pB = pairs[j + 2];
        uint2 wA = *(const uint2*)(xbase + pA.x);
        uint2 wB = *(const uint2*)(xbase + pB.x);
        float vA = __int_as_float(pA.y), vB = __int_as_float(pB.y);
        a0 = fmaf(vA, bflo(wA.x), a0); a1 = fmaf(vA, bfhi(wA.x), a1);
        a2 = fmaf(vA, bflo(wA.y), a2); a3 = fmaf(vA, bfhi(wA.y), a3);
        a0 = fmaf(vB, bflo(wB.x), a0); a1 = fmaf(vB, bfhi(wB.x), a1);
        a2 = fmaf(vB, bflo(wB.y), a2); a3 = fmaf(vB, bfhi(wB.y), a3);
    }
    if (j < end) {
        int2 p = pairs[j];
        uint2 w = *(const uint2*)(xbase + p.x);
        float v = __int_as_float(p.y);
        a0 = fmaf(v, bflo(w.x), a0); a1 = fmaf(v, bfhi(w.x), a1);
        a2 = fmaf(v, bflo(w.y), a2); a3 = fmaf(v, bfhi(w.y), a3);
    }
    a0 += __shfl_xor(a0, 32); a1 += __shfl_xor(a1, 32);
    a2 += __shfl_xor(a2, 32); a3 += __shfl_xor(a3, 32);
    if (hw == 0) {
        uint2 ws = *(const uint2*)(xbase + (size_t)n * 256);
        float sc = 1.0f + eps[0];
        a0 = fmaf(sc, bflo(ws.x), a0); a1 = fmaf(sc, bfhi(ws.x), a1);
        a2 = fmaf(sc, bflo(ws.y), a2); a3 = fmaf(sc, bfhi(ws.y), a3);
        __bf16 b0 = (__bf16)a0, b1 = (__bf16)a1, b2 = (__bf16)a2, b3 = (__bf16)a3;
        uint2 o;
        o.x = (unsigned)*(unsigned short*)&b0 | ((unsigned)*(unsigned short*)&b1 << 16);
        o.y = (unsigned)*(unsigned short*)&b2 | ((unsigned)*(unsigned short*)&b3 << 16);
        AXb[(size_t)n * 32 + l32] = o;
    }
}

// ---------------- fallback path (atomic scatter, fp32 AX in d_out) ----------------
__global__ void init_ax_kernel(const float4* __restrict__ x, float4* __restrict__ AX,
                               const float* __restrict__ eps, int n4) {
    int i = blockIdx.x * blockDim.x + threadIdx.x;
    if (i >= n4) return;
    float s = 1.0f + eps[0];
    float4 v = x[i];
    v.x *= s; v.y *= s; v.z *= s; v.w *= s;
    AX[i] = v;
}

__global__ void scatter_kernel(const float2* __restrict__ x2, const float* __restrict__ ev,
                               const int* __restrict__ esrc, const int* __restrict__ edst,
                               float* AX) {
    unsigned gid = blockIdx.x * 256u + threadIdx.x;
    unsigned e = gid >> 6;
    unsigned lane = gid & 63u;
    if (e >= NE) return;
    float v = ev[e];
    int s = esrc[e], d = edst[e];
    float2 xv = x2[(size_t)s * 64 + lane];
    float* dstp = AX + (size_t)d * 128 + lane * 2;
    atomicAdd(dstp,     v * xv.x);
    atomicAdd(dstp + 1, v * xv.y);
}

// ---------------- fused 2-layer MLP: out = relu(A@W1+b1)@W2+b2, A is bf16 or fp32 ----------------
template <typename AT>
__global__ __launch_bounds__(256) void mlp_kernel(const AT* A,
                                                  const __bf16* __restrict__ W1T,
                                                  const __bf16* __restrict__ W2T,
                                                  const float* __restrict__ b1,
                                                  const float* __restrict__ b2,
                                                  float* out) {
    __shared__ __bf16 Hl[64][264];

    const int wave = threadIdx.x >> 6;
    const int lane = threadIdx.x & 63;
    const int l15  = lane & 15;
    const int lhi  = lane >> 4;
    const int rowbase = blockIdx.x * 64;

    f32x4 acc1[4][4] = {};
#pragma unroll
    for (int ks = 0; ks < 4; ++ks) {
        const int k0 = ks * 32 + lhi * 8;
        bf16x8 am[4], bn[4];
#pragma unroll
        for (int mt = 0; mt < 4; ++mt) {
            int row = rowbase + mt * 16 + l15;
            if (row >= NN) row = NN - 1;
            if constexpr (std::is_same<AT, __bf16>::value) {
                am[mt] = *(const bf16x8*)(A + (size_t)row * 128 + k0);
            } else {
                const float4* ap = (const float4*)(A + (size_t)row * 128 + k0);
                float4 f0 = ap[0], f1 = ap[1];
                bf16x8 a;
                a[0]=(__bf16)f0.x; a[1]=(__bf16)f0.y; a[2]=(__bf16)f0.z; a[3]=(__bf16)f0.w;
                a[4]=(__bf16)f1.x; a[5]=(__bf16)f1.y; a[6]=(__bf16)f1.z; a[7]=(__bf16)f1.w;
                am[mt] = a;
            }
        }
#pragma unroll
        for (int nt = 0; nt < 4; ++nt) {
            int n = wave * 64 + nt * 16 + l15;
            bn[nt] = *(const bf16x8*)(W1T + (size_t)n * 128 + k0);
        }
#pragma unroll
        for (int mt = 0; mt < 4; ++mt)
#pragma unroll
            for (int nt = 0; nt < 4; ++nt)
                acc1[mt][nt] = __builtin_amdgcn_mfma_f32_16x16x32_bf16(am[mt], bn[nt], acc1[mt][nt], 0, 0, 0);
    }

#pragma unroll
    for (int nt = 0; nt < 4; ++nt) {
        int n = wave * 64 + nt * 16 + l15;
        float bias = b1[n];
#pragma unroll
        for (int mt = 0; mt < 4; ++mt)
#pragma unroll
            for (int r = 0; r < 4; ++r) {
                float h = acc1[mt][nt][r] + bias;
                Hl[mt * 16 + lhi * 4 + r][n] = (__bf16)fmaxf(h, 0.0f);
            }
    }
    __syncthreads();

    f32x4 acc2[4][2] = {};
#pragma unroll
    for (int ks = 0; ks < 8; ++ks) {
        const int k0 = ks * 32 + lhi * 8;
        bf16x8 ha[4], wb[2];
#pragma unroll
        for (int mt = 0; mt < 4; ++mt)
            ha[mt] = *(const bf16x8*)(&Hl[mt * 16 + l15][k0]);
#pragma unroll
        for (int nt = 0; nt < 2; ++nt) {
            int n = wave * 32 + nt * 16 + l15;
            wb[nt] = *(const bf16x8*)(W2T + (size_t)n * 256 + k0);
        }
#pragma unroll
        for (int mt = 0; mt < 4; ++mt)
#pragma unroll
            for (int nt = 0; nt < 2; ++nt)
                acc2[mt][nt] = __builtin_amdgcn_mfma_f32_16x16x32_bf16(ha[mt], wb[nt], acc2[mt][nt], 0, 0, 0);
    }

#pragma unroll
    for (int nt = 0; nt < 2; ++nt) {
        int n = wave * 32 + nt * 16 + l15;
        float bias = b2[n];
#pragma unroll
        for (int mt = 0; mt < 4; ++mt)
#pragma unroll
            for (int r = 0; r < 4; ++r) {
                int row = rowbase + mt * 16 + lhi * 4 + r;
                if (row < NN) out[(size_t)row * 128 + n] = acc2[mt][nt][r] + bias;
            }
    }
}

extern "C" void kernel_launch(void* const* d_in, const int* in_sizes, int n_in,
                              void* d_out, int out_size, void* d_ws, size_t ws_size,
                              hipStream_t stream) {
    const float* x    = (const float*)d_in[0];
    const float* ev   = (const float*)d_in[1];
    const float* W1   = (const float*)d_in[2];
    const float* b1   = (const float*)d_in[3];
    const float* W2   = (const float*)d_in[4];
    const float* b2   = (const float*)d_in[5];
    const float* eps  = (const float*)d_in[6];
    const int*   esrc = (const int*)d_in[7];
    const int*   edst = (const int*)d_in[8];
    float* out = (float*)d_out;

    char* ws = (char*)d_ws;
    size_t off = 0;
    auto alloc = [&](size_t bytes) { void* p = ws + off; off += (bytes + 511) & ~size_t(511); return p; };

    __bf16* W1T     = (__bf16*)alloc(128 * 256 * sizeof(__bf16));
    __bf16* W2T     = (__bf16*)alloc(128 * 256 * sizeof(__bf16));
    int* cnt8       = (int*)  alloc((size_t)8 * NBUCK * sizeof(int));
    int* bucket_off = (int*)  alloc((NBUCK + 1) * sizeof(int));
    int* cursor8    = (int*)  alloc((size_t)8 * NBUCK * sizeof(int));
    int* node_off   = (int*)  alloc((size_t)(NBUCK * 64 + 1) * sizeof(int));
    int2* pairs_t   = (int2*) alloc((size_t)NE * sizeof(int2));
    int2* pairs2    = (int2*) alloc((size_t)NE * sizeof(int2));
    unsigned* xb    = (unsigned*)alloc((size_t)NN * 64 * sizeof(unsigned));   // bf16 x
    unsigned* AXb   = (unsigned*)alloc((size_t)NN * 64 * sizeof(unsigned));   // bf16 AX
    bool csr_ok = (off <= ws_size);

    int nblk = (NN + 63) / 64;   // 1563
    if (csr_ok) {
        int cblocks = 128 + (NN * 32 + 255) / 256;   // weights + x converts
        convert_kernel<<<cblocks, 256, 0, stream>>>(W1, W2, W1T, W2T, (const float4*)x, (uint2*)xb);
        hipMemsetAsync(cnt8, 0, (size_t)8 * NBUCK * sizeof(int), stream);
        hist_bucket8<<<2048, 256, 0, stream>>>(edst, cnt8);
        scan_all<<<1, 256, 0, stream>>>(cnt8, bucket_off, cursor8);
        reorder_bucket8<<<2048, 256, 0, stream>>>(esrc, edst, ev, cursor8, pairs_t);
        local_sort_kernel<<<NBUCK, 256, 0, stream>>>(bucket_off, pairs_t, pairs2, node_off);
        gather_reduce_kernel<<<(NN * 64 + 255) / 256, 256, 0, stream>>>(
            xb, node_off, pairs2, eps, (uint2*)AXb);
        mlp_kernel<__bf16><<<nblk, 256, 0, stream>>>((const __bf16*)AXb, W1T, W2T, b1, b2, out);
    } else {
        // fallback: atomic scatter path (fp32 AX in d_out)
        __bf16* W1Tf = (__bf16*)ws;
        __bf16* W2Tf = W1Tf + 128 * 256;
        convert_kernel<<<128, 256, 0, stream>>>(W1, W2, W1Tf, W2Tf, (const float4*)x, (uint2*)nullptr);
        int n4 = NN * 128 / 4;
        init_ax_kernel<<<(n4 + 255) / 256, 256, 0, stream>>>((const float4*)x, (float4*)out, eps, n4);
        scatter_kernel<<<(NE * 64u) / 256u, 256, 0, stream>>>((const float2*)x, ev, esrc, edst, out);
        mlp_kernel<float><<<nblk, 256, 0, stream>>>(out, W1Tf, W2Tf, b1, b2, out);
    }
}